// Round 7
// baseline (217.918 us; speedup 1.0000x reference)
//
#include <hip/hip_runtime.h>
#include <cmath>

// B=1, H=64, W=128, C=256, 8 heads x 32 dim, 7x7 window.
#define HH 64
#define WW 128
#define CC 256
#define NHEAD 8
#define HDIM 32
#define NPIX (HH*WW)       // 8192
#define QKV_N (3*CC)       // 768
#define NBLK 512u          // co-resident by construction (see launch_bounds note)

#define KSLOT 248
#define LDK   40
#define VSLOT 264

typedef __attribute__((ext_vector_type(8))) short short8v;  // 8 bf16
typedef __attribute__((ext_vector_type(4))) short short4v;  // 4 bf16
typedef __attribute__((ext_vector_type(4))) float f32x4;
typedef unsigned int u32;

__device__ __forceinline__ short f2bf(float f) {
    unsigned int u = __builtin_bit_cast(unsigned int, f);
    u += 0x7fffu + ((u >> 16) & 1u);
    return (short)(u >> 16);
}

// Shared-LDS union across phases: na needs 36736 B (max).
union SharedU {
    short raw[18368];        // 36736 B
    float tile[32][33];      // prep transpose scratch
};

// ---------------------------------------------------------------------------
// Device-scope grid barrier: atomic counter + generation, acquire/release.
// All 512 blocks are co-resident (LDS 36.7KB -> 4/CU; launch_bounds(256,2)
// caps VGPR at 128 -> >=2 blocks/CU; 2*256 CUs = 512), so no deadlock.
// cnt/gen are zeroed by an 8-byte hipMemsetAsync before each launch.
// ---------------------------------------------------------------------------
__device__ __forceinline__ void grid_sync(u32* cnt, u32* gen)
{
    __syncthreads();
    if (threadIdx.x == 0) {
        u32 my = __hip_atomic_load(gen, __ATOMIC_ACQUIRE, __HIP_MEMORY_SCOPE_AGENT);
        u32 prev = __hip_atomic_fetch_add(cnt, 1u, __ATOMIC_ACQ_REL, __HIP_MEMORY_SCOPE_AGENT);
        if (prev == NBLK - 1u) {
            __hip_atomic_store(cnt, 0u, __ATOMIC_RELAXED, __HIP_MEMORY_SCOPE_AGENT);
            __hip_atomic_fetch_add(gen, 1u, __ATOMIC_ACQ_REL, __HIP_MEMORY_SCOPE_AGENT);
        } else {
            while (__hip_atomic_load(gen, __ATOMIC_ACQUIRE, __HIP_MEMORY_SCOPE_AGENT) == my)
                __builtin_amdgcn_s_sleep(2);
        }
    }
    __syncthreads();
}

// ---------------------------------------------------------------------------
// bf16 MFMA GEMM tile (round-6 structure: gload_lds direct staging, dbuf).
// PLANE: store C column n as plane p=n>>5 of [24][NPIX][32] (qkv layout).
// ---------------------------------------------------------------------------
template<int BM, int BN, bool OUT32, bool PLANE>
__device__ __forceinline__ void gemm_tile(short* lds,
    const short* __restrict__ A, const short* __restrict__ Bt,
    const float* __restrict__ bias, void* __restrict__ Cv,
    int N, int K, int bm, int bn)
{
    constexpr int BK  = 32;
    constexpr int NGA = BM * BK / 2048;
    constexpr int NGB = BN * BK / 2048;
    short* As = lds;                    // [2][BM*BK]
    short* Bs = lds + 2 * BM * BK;      // [2][BN*BK]

    const int tid  = threadIdx.x;
    const int lane = tid & 63;
    const int wave = tid >> 6;
    constexpr int WM = BM / 2, WN = BN / 2;
    constexpr int FM = WM / 16, FN = WN / 16;
    const int wm0 = (wave >> 1) * WM;
    const int wn0 = (wave & 1) * WN;
    const int l15 = lane & 15, l4 = lane >> 4;

    f32x4 acc[FM][FN];
#pragma unroll
    for (int i = 0; i < FM; ++i)
#pragma unroll
        for (int j = 0; j < FN; ++j) acc[i][j] = (f32x4){0.f, 0.f, 0.f, 0.f};

    auto stage = [&](int buf, int t) {
#pragma unroll
        for (int i = 0; i < NGA; ++i) {
            const int g = tid + 256 * i;
            __builtin_amdgcn_global_load_lds(
                (const __attribute__((address_space(1))) u32*)
                    (A + (size_t)(bm + (g >> 2)) * K + t * BK + (g & 3) * 8),
                (__attribute__((address_space(3))) u32*)&As[buf * BM * BK + g * 8],
                16, 0, 0);
        }
#pragma unroll
        for (int i = 0; i < NGB; ++i) {
            const int g = tid + 256 * i;
            __builtin_amdgcn_global_load_lds(
                (const __attribute__((address_space(1))) u32*)
                    (Bt + (size_t)(bn + (g >> 2)) * K + t * BK + (g & 3) * 8),
                (__attribute__((address_space(3))) u32*)&Bs[buf * BN * BK + g * 8],
                16, 0, 0);
        }
    };

    stage(0, 0);
    const int NT = K / BK;

    for (int t = 0; t < NT; ++t) {
        const int cur = t & 1;
        __syncthreads();                 // stage(t) landed; prior buf reads done
        if (t + 1 < NT) stage(cur ^ 1, t + 1);

        short8v af[FM], bf[FN];
#pragma unroll
        for (int fm = 0; fm < FM; ++fm)
            af[fm] = *(const short8v*)&As[cur * BM * BK + (wm0 + fm * 16 + l15) * BK + l4 * 8];
#pragma unroll
        for (int fn = 0; fn < FN; ++fn)
            bf[fn] = *(const short8v*)&Bs[cur * BN * BK + (wn0 + fn * 16 + l15) * BK + l4 * 8];
#pragma unroll
        for (int fm = 0; fm < FM; ++fm)
#pragma unroll
            for (int fn = 0; fn < FN; ++fn)
                acc[fm][fn] = __builtin_amdgcn_mfma_f32_16x16x32_bf16(
                    af[fm], bf[fn], acc[fm][fn], 0, 0, 0);
    }

    const int col0 = bn + wn0 + l15;
    const int row0 = bm + wm0 + l4 * 4;
#pragma unroll
    for (int fn = 0; fn < FN; ++fn) {
        const float bv = bias[col0 + fn * 16];
#pragma unroll
        for (int fm = 0; fm < FM; ++fm)
#pragma unroll
            for (int r = 0; r < 4; ++r) {
                const int rr = row0 + fm * 16 + r;
                const float v = acc[fm][fn][r] + bv;
                if (PLANE) {
                    const int cc = col0 + fn * 16;
                    ((short*)Cv)[((size_t)(cc >> 5) * NPIX + rr) * HDIM + (cc & 31)] = f2bf(v);
                } else if (OUT32) {
                    ((float*)Cv)[(size_t)rr * N + col0 + fn * 16] = v;
                } else {
                    ((short*)Cv)[(size_t)rr * N + col0 + fn * 16] = f2bf(v);
                }
            }
    }
}

// ---------------------------------------------------------------------------
// Neighborhood attention tile (round-6 math verbatim; plane-layout reads:
// K/V/Q staging is now contiguous 1KB-per-wave instead of 64B @1536B stride).
// ---------------------------------------------------------------------------
__device__ __forceinline__ void na_tile(short* lds, const short* __restrict__ qkv,
                                        short* __restrict__ attn,
                                        int x0, int y0, int head)
{
    short* Ksh = lds;                    // KSLOT*LDK shorts
    short* Vsh = lds + KSLOT * LDK;      // 32*VSLOT shorts  [d][slot]

    const int tid = threadIdx.x, lane = tid & 63, w = tid >> 6;
    const int rs  = min(max(y0 - 3, 0), HH - 7);
    const int wsx = x0 - 3;
    const short* Qp = qkv + (size_t)head * NPIX * HDIM;
    const short* Kp = qkv + (size_t)(NHEAD + head) * NPIX * HDIM;
    const short* Vp = qkv + (size_t)(2 * NHEAD + head) * NPIX * HDIM;

    // ---- stage K (fully coalesced: g fastest -> consecutive 16B) ----
    for (int idx = tid; idx < 880; idx += 256) {
        int g = idx & 3, rc = idx >> 2;
        int i = rc / 22, c = rc - i * 22;
        int yy = rs + i, xx = wsx + c;
        if (yy < HH && (unsigned)xx < WW)
            *(short8v*)&Ksh[(i * 24 + c) * LDK + g * 8] =
                *(const short8v*)(Kp + (size_t)(yy * WW + xx) * HDIM + g * 8);
    }
    // ---- stage V^T (zero-fills all 264 slots) ----
    for (int idx = tid; idx < 264; idx += 256) {
        int g = idx & 3, q2 = idx >> 2;
        int i = q2 / 6, cq = q2 - i * 6;
        int yy = rs + i;
        short8v vv[4];
#pragma unroll
        for (int j = 0; j < 4; ++j) {
            int c = cq * 4 + j, xx = wsx + c;
            if (yy < HH && c < 22 && (unsigned)xx < WW)
                vv[j] = *(const short8v*)(Vp + (size_t)(yy * WW + xx) * HDIM + g * 8);
            else {
                short8v z = {0,0,0,0,0,0,0,0};
                vv[j] = z;
            }
        }
#pragma unroll
        for (int jd = 0; jd < 8; ++jd) {
            short4v s4 = {vv[0][jd], vv[1][jd], vv[2][jd], vv[3][jd]};
            *(short4v*)&Vsh[(g * 8 + jd) * VSLOT + i * 24 + cq * 4] = s4;
        }
    }

    const int l15 = lane & 15, l4 = lane >> 4;
    const int y = y0 + w;
    short8v qf = *(const short8v*)(Qp + (size_t)(y * WW + x0 + l15) * HDIM + l4 * 8);
    __syncthreads();

    const int wbase = (min(max(y - 3, 0), HH - 7) - rs) * 24;

    // ---- S^T = mfma(K, Q): 11 frags over 176 slots ----
    f32x4 sacc[11];
#pragma unroll
    for (int kc = 0; kc < 11; ++kc) {
        short8v kf = *(const short8v*)&Ksh[(wbase + kc * 16 + l15) * LDK + l4 * 8];
        f32x4 z = {0.f, 0.f, 0.f, 0.f};
        sacc[kc] = __builtin_amdgcn_mfma_f32_16x16x32_bf16(kf, qf, z, 0, 0, 0);
    }

    // ---- mask + exp + row-sum ----
    const int xq = x0 + l15;
    const int cw = min(max(xq - 3, 0), WW - 7) - wsx;
    const float scale = 0.17677669529663687f;
    float lsum = 0.f;
#pragma unroll
    for (int kc = 0; kc < 11; ++kc) {
#pragma unroll
        for (int r = 0; r < 4; ++r) {
            int kl = kc * 16 + l4 * 4 + r;
            int row = kl / 24;
            int c = kl - row * 24;
            bool valid = (row < 7) && (c >= cw) && (c <= cw + 6);
            float e = valid ? __expf(sacc[kc][r] * scale) : 0.f;
            sacc[kc][r] = e;
            lsum += e;
        }
    }
    lsum += __shfl_xor(lsum, 16);
    lsum += __shfl_xor(lsum, 32);
    const float inv = 1.0f / lsum;

    short4v pf[12];
#pragma unroll
    for (int kc = 0; kc < 11; ++kc) {
        short4v pk;
#pragma unroll
        for (int r = 0; r < 4; ++r) pk[r] = f2bf(sacc[kc][r] * inv);
        pf[kc] = pk;
    }
    pf[11] = (short4v){0, 0, 0, 0};

    // ---- O^T = mfma(V^T, P^T), P^T frags via shfl ----
    const int src0 = ((l4 & 1) << 5) + l15;
    const int src1 = src0 + 16;
    const bool hi = (l4 & 2) != 0;
    f32x4 oacc[2];
    oacc[0] = (f32x4){0.f, 0.f, 0.f, 0.f};
    oacc[1] = (f32x4){0.f, 0.f, 0.f, 0.f};
#pragma unroll
    for (int kc2 = 0; kc2 < 6; ++kc2) {
        int lo0 = ((const int*)&pf[2 * kc2])[0];
        int lo1 = ((const int*)&pf[2 * kc2])[1];
        int hi0 = ((const int*)&pf[2 * kc2 + 1])[0];
        int hi1 = ((const int*)&pf[2 * kc2 + 1])[1];
        int a0 = __shfl(lo0, src0), a1 = __shfl(lo1, src0);
        int a2 = __shfl(lo0, src1), a3 = __shfl(lo1, src1);
        int b0 = __shfl(hi0, src0), b1 = __shfl(hi1, src0);
        int b2 = __shfl(hi0, src1), b3 = __shfl(hi1, src1);
        int w0 = hi ? b0 : a0, w1 = hi ? b1 : a1;
        int w2 = hi ? b2 : a2, w3 = hi ? b3 : a3;
        int wv[4] = {w0, w1, w2, w3};
        short8v bfrag = *(const short8v*)wv;
#pragma unroll
        for (int nc = 0; nc < 2; ++nc) {
            short8v vf = *(const short8v*)&Vsh[(nc * 16 + l15) * VSLOT
                                               + wbase + kc2 * 32 + l4 * 8];
            oacc[nc] = __builtin_amdgcn_mfma_f32_16x16x32_bf16(vf, bfrag, oacc[nc], 0, 0, 0);
        }
    }

    short* op = attn + (size_t)(y * WW + x0 + l15) * CC + head * HDIM;
#pragma unroll
    for (int nc = 0; nc < 2; ++nc) {
        short4v o;
#pragma unroll
        for (int r = 0; r < 4; ++r) o[r] = f2bf(oacc[nc][r]);
        *(short4v*)(op + nc * 16 + l4 * 4) = o;
    }
}

// ---------------------------------------------------------------------------
// The fused pipeline: prep -> QKV GEMM -> NA -> proj, grid-synced.
// ---------------------------------------------------------------------------
__global__ __launch_bounds__(256, 2)
void fused(const float* __restrict__ x, const float* __restrict__ w_qkv,
           const float* __restrict__ b_qkv, const float* __restrict__ w_proj,
           const float* __restrict__ b_proj, float* __restrict__ out,
           short* __restrict__ x_bf, short* __restrict__ wq_t,
           short* __restrict__ wp_t, short* __restrict__ qkv_r,
           short* __restrict__ attn_bf, u32* cnt, u32* gen)
{
    __shared__ SharedU sh;
    const int bid = blockIdx.x;
    const int tid = threadIdx.x;

    // ---- phase 0: x -> bf16 (1024 units) + weight transposes (256 units) ----
    for (int vb = bid; vb < 1280; vb += (int)NBLK) {
        if (vb < 1024) {
            const int i = vb * 256 + tid;
            float4 a = ((const float4*)x)[i * 2];
            float4 c = ((const float4*)x)[i * 2 + 1];
            short8v o;
            o[0] = f2bf(a.x); o[1] = f2bf(a.y); o[2] = f2bf(a.z); o[3] = f2bf(a.w);
            o[4] = f2bf(c.x); o[5] = f2bf(c.y); o[6] = f2bf(c.z); o[7] = f2bf(c.w);
            ((short8v*)x_bf)[i] = o;
        } else {
            int idx = vb - 1024;
            const float* src; short* dst; int N;
            if (idx < 192) { src = w_qkv;  dst = wq_t; N = QKV_N; }
            else { idx -= 192; src = w_proj; dst = wp_t; N = CC; }
            const int nbx = N / 32;
            const int bn = (idx % nbx) * 32;
            const int bk = (idx / nbx) * 32;
            const int tx = tid & 31, ty = tid >> 5;
#pragma unroll
            for (int i = 0; i < 32; i += 8)
                sh.tile[ty + i][tx] = src[(size_t)(bk + ty + i) * N + bn + tx];
            __syncthreads();
#pragma unroll
            for (int i = 0; i < 32; i += 8)
                dst[(size_t)(bn + ty + i) * CC + bk + tx] = f2bf(sh.tile[tx][ty + i]);
        }
    }
    grid_sync(cnt, gen);

    // ---- phase 1: QKV GEMM, 768 tiles of 64x128 over 512 blocks ----
    for (int vt = bid; vt < 768; vt += (int)NBLK) {
        const int m = vt & 127, n = vt >> 7;
        gemm_tile<64, 128, false, true>(sh.raw, x_bf, wq_t, b_qkv, qkv_r,
                                        QKV_N, CC, m * 64, n * 128);
        __syncthreads();
    }
    grid_sync(cnt, gen);

    // ---- phase 2: neighborhood attention, 1024 tiles over 512 blocks ----
    for (int vt = bid; vt < 1024; vt += (int)NBLK) {
        na_tile(sh.raw, qkv_r, attn_bf, (vt & 7) * 16, ((vt >> 3) & 15) * 4, vt >> 7);
        __syncthreads();
    }
    grid_sync(cnt, gen);

    // ---- phase 3: proj GEMM, 512 tiles of 64x64, 1:1 ----
    {
        const int vt = bid;
        gemm_tile<64, 64, true, false>(sh.raw, attn_bf, wp_t, b_proj, out,
                                       CC, CC, (vt & 127) * 64, (vt >> 7) * 64);
    }
}

// ---------------------------------------------------------------------------
extern "C" void kernel_launch(void* const* d_in, const int* in_sizes, int n_in,
                              void* d_out, int out_size, void* d_ws, size_t ws_size,
                              hipStream_t stream)
{
    const float* x      = (const float*)d_in[0];
    const float* w_qkv  = (const float*)d_in[1];
    const float* b_qkv  = (const float*)d_in[2];
    const float* w_proj = (const float*)d_in[3];
    const float* b_proj = (const float*)d_in[4];
    float* out = (float*)d_out;

    char* ws = (char*)d_ws;
    short* qkv_r   = (short*)ws;                    // 24 planes x 8192 x 32 bf16 = 12 MB
    short* attn_bf = (short*)(ws + 12582912);       // 8192x256 bf16 = 4 MB
    short* x_bf    = (short*)(ws + 16777216);       // 8192x256 bf16 = 4 MB
    short* wq_t    = (short*)(ws + 20971520);       // 768x256 bf16
    short* wp_t    = (short*)(ws + 21364736);       // 256x256 bf16
    u32*   syncv   = (u32*)(ws + 21495808);         // {cnt, gen}

    hipMemsetAsync(syncv, 0, 8, stream);            // zero barrier state each launch
    fused<<<dim3(NBLK), dim3(256), 0, stream>>>(
        x, w_qkv, b_qkv, w_proj, b_proj, out,
        x_bf, wq_t, wp_t, qkv_r, attn_bf, syncv, syncv + 1);
}

// Round 8
// 103.244 us; speedup vs baseline: 2.1107x; 2.1107x over previous
//
#include <hip/hip_runtime.h>
#include <cmath>

// B=1, H=64, W=128, C=256, 8 heads x 32 dim, 7x7 window.
#define HH 64
#define WW 128
#define CC 256
#define NHEAD 8
#define HDIM 32
#define NPIX (HH*WW)       // 8192
#define QKV_N (3*CC)       // 768
#define NBLK 512u          // co-resident: LDS 36.7KB->4/CU, VGPR<=128 -> >=2/CU

#define KSLOT 248
#define LDK   40
#define VSLOT 264

typedef __attribute__((ext_vector_type(8))) short short8v;  // 8 bf16
typedef __attribute__((ext_vector_type(4))) short short4v;  // 4 bf16
typedef __attribute__((ext_vector_type(4))) float f32x4;
typedef unsigned int u32;

__device__ __forceinline__ short f2bf(float f) {
    unsigned int u = __builtin_bit_cast(unsigned int, f);
    u += 0x7fffu + ((u >> 16) & 1u);
    return (short)(u >> 16);
}

union SharedU {
    short raw[18368];        // 36736 B (na_tile max)
    float tile[32][33];      // prep transpose scratch
};

// ---------------------------------------------------------------------------
// Grid barrier, contention- and cache-maintenance-aware (round-7 fix):
//  - arrivals: RELEASE fetch_add (writeback only; publishes phase writes)
//    on 8 sub-counters spaced 128B (bid&7) -> 64 RMWs/line, then last-of-8
//    promotes to top; last-of-top RELEASE-stores flag = bar.
//  - spin: RELAXED polls (coherent read, NO invalidate) + s_sleep(32);
//    ONE ACQUIRE load after exit (single L1/L2 inv per block per barrier).
//  Round 7 polled with ACQUIRE every ~130cy: 512 spinners x full L2 inv
//  storm + cnt/gen false sharing = 200us of dead time.
//  Counters are monotonic (no resets): barrier `bar` (1-based) completes
//  sub at bar*64, top at bar*8.
// ---------------------------------------------------------------------------
__device__ __forceinline__ void grid_sync(u32* syncb, u32 bar, int bid)
{
    __syncthreads();
    if (threadIdx.x == 0) {
        u32* sub  = syncb + (bid & 7) * 32;    // 128-B spacing
        u32* top  = syncb + 8 * 32;
        u32* flag = syncb + 9 * 32;
        u32 prev = __hip_atomic_fetch_add(sub, 1u, __ATOMIC_RELEASE,
                                          __HIP_MEMORY_SCOPE_AGENT);
        if (prev == bar * (NBLK / 8u) - 1u) {
            u32 p2 = __hip_atomic_fetch_add(top, 1u, __ATOMIC_RELEASE,
                                            __HIP_MEMORY_SCOPE_AGENT);
            if (p2 == bar * 8u - 1u)
                __hip_atomic_store(flag, bar, __ATOMIC_RELEASE,
                                   __HIP_MEMORY_SCOPE_AGENT);
        }
        while (__hip_atomic_load(flag, __ATOMIC_RELAXED,
                                 __HIP_MEMORY_SCOPE_AGENT) < bar)
            __builtin_amdgcn_s_sleep(32);
        (void)__hip_atomic_load(flag, __ATOMIC_ACQUIRE,
                                __HIP_MEMORY_SCOPE_AGENT);   // one inv
    }
    __syncthreads();
}

// ---------------------------------------------------------------------------
// bf16 MFMA GEMM tile (gload_lds direct staging, dbuf) — unchanged.
// PLANE: store C column n as plane p=n>>5 of [24][NPIX][32] (qkv layout).
// ---------------------------------------------------------------------------
template<int BM, int BN, bool OUT32, bool PLANE>
__device__ __forceinline__ void gemm_tile(short* lds,
    const short* __restrict__ A, const short* __restrict__ Bt,
    const float* __restrict__ bias, void* __restrict__ Cv,
    int N, int K, int bm, int bn)
{
    constexpr int BK  = 32;
    constexpr int NGA = BM * BK / 2048;
    constexpr int NGB = BN * BK / 2048;
    short* As = lds;                    // [2][BM*BK]
    short* Bs = lds + 2 * BM * BK;      // [2][BN*BK]

    const int tid  = threadIdx.x;
    const int lane = tid & 63;
    const int wave = tid >> 6;
    constexpr int WM = BM / 2, WN = BN / 2;
    constexpr int FM = WM / 16, FN = WN / 16;
    const int wm0 = (wave >> 1) * WM;
    const int wn0 = (wave & 1) * WN;
    const int l15 = lane & 15, l4 = lane >> 4;

    f32x4 acc[FM][FN];
#pragma unroll
    for (int i = 0; i < FM; ++i)
#pragma unroll
        for (int j = 0; j < FN; ++j) acc[i][j] = (f32x4){0.f, 0.f, 0.f, 0.f};

    auto stage = [&](int buf, int t) {
#pragma unroll
        for (int i = 0; i < NGA; ++i) {
            const int g = tid + 256 * i;
            __builtin_amdgcn_global_load_lds(
                (const __attribute__((address_space(1))) u32*)
                    (A + (size_t)(bm + (g >> 2)) * K + t * BK + (g & 3) * 8),
                (__attribute__((address_space(3))) u32*)&As[buf * BM * BK + g * 8],
                16, 0, 0);
        }
#pragma unroll
        for (int i = 0; i < NGB; ++i) {
            const int g = tid + 256 * i;
            __builtin_amdgcn_global_load_lds(
                (const __attribute__((address_space(1))) u32*)
                    (Bt + (size_t)(bn + (g >> 2)) * K + t * BK + (g & 3) * 8),
                (__attribute__((address_space(3))) u32*)&Bs[buf * BN * BK + g * 8],
                16, 0, 0);
        }
    };

    stage(0, 0);
    const int NT = K / BK;

    for (int t = 0; t < NT; ++t) {
        const int cur = t & 1;
        __syncthreads();                 // stage(t) landed; prior buf reads done
        if (t + 1 < NT) stage(cur ^ 1, t + 1);

        short8v af[FM], bf[FN];
#pragma unroll
        for (int fm = 0; fm < FM; ++fm)
            af[fm] = *(const short8v*)&As[cur * BM * BK + (wm0 + fm * 16 + l15) * BK + l4 * 8];
#pragma unroll
        for (int fn = 0; fn < FN; ++fn)
            bf[fn] = *(const short8v*)&Bs[cur * BN * BK + (wn0 + fn * 16 + l15) * BK + l4 * 8];
#pragma unroll
        for (int fm = 0; fm < FM; ++fm)
#pragma unroll
            for (int fn = 0; fn < FN; ++fn)
                acc[fm][fn] = __builtin_amdgcn_mfma_f32_16x16x32_bf16(
                    af[fm], bf[fn], acc[fm][fn], 0, 0, 0);
    }

    const int col0 = bn + wn0 + l15;
    const int row0 = bm + wm0 + l4 * 4;
#pragma unroll
    for (int fn = 0; fn < FN; ++fn) {
        const float bv = bias[col0 + fn * 16];
#pragma unroll
        for (int fm = 0; fm < FM; ++fm)
#pragma unroll
            for (int r = 0; r < 4; ++r) {
                const int rr = row0 + fm * 16 + r;
                const float v = acc[fm][fn][r] + bv;
                if (PLANE) {
                    const int cc = col0 + fn * 16;
                    ((short*)Cv)[((size_t)(cc >> 5) * NPIX + rr) * HDIM + (cc & 31)] = f2bf(v);
                } else if (OUT32) {
                    ((float*)Cv)[(size_t)rr * N + col0 + fn * 16] = v;
                } else {
                    ((short*)Cv)[(size_t)rr * N + col0 + fn * 16] = f2bf(v);
                }
            }
    }
}

// ---------------------------------------------------------------------------
// Neighborhood attention tile (unchanged math; plane-layout reads).
// ---------------------------------------------------------------------------
__device__ __forceinline__ void na_tile(short* lds, const short* __restrict__ qkv,
                                        short* __restrict__ attn,
                                        int x0, int y0, int head)
{
    short* Ksh = lds;                    // KSLOT*LDK shorts
    short* Vsh = lds + KSLOT * LDK;      // 32*VSLOT shorts  [d][slot]

    const int tid = threadIdx.x, lane = tid & 63, w = tid >> 6;
    const int rs  = min(max(y0 - 3, 0), HH - 7);
    const int wsx = x0 - 3;
    const short* Qp = qkv + (size_t)head * NPIX * HDIM;
    const short* Kp = qkv + (size_t)(NHEAD + head) * NPIX * HDIM;
    const short* Vp = qkv + (size_t)(2 * NHEAD + head) * NPIX * HDIM;

    for (int idx = tid; idx < 880; idx += 256) {
        int g = idx & 3, rc = idx >> 2;
        int i = rc / 22, c = rc - i * 22;
        int yy = rs + i, xx = wsx + c;
        if (yy < HH && (unsigned)xx < WW)
            *(short8v*)&Ksh[(i * 24 + c) * LDK + g * 8] =
                *(const short8v*)(Kp + (size_t)(yy * WW + xx) * HDIM + g * 8);
    }
    for (int idx = tid; idx < 264; idx += 256) {
        int g = idx & 3, q2 = idx >> 2;
        int i = q2 / 6, cq = q2 - i * 6;
        int yy = rs + i;
        short8v vv[4];
#pragma unroll
        for (int j = 0; j < 4; ++j) {
            int c = cq * 4 + j, xx = wsx + c;
            if (yy < HH && c < 22 && (unsigned)xx < WW)
                vv[j] = *(const short8v*)(Vp + (size_t)(yy * WW + xx) * HDIM + g * 8);
            else {
                short8v z = {0,0,0,0,0,0,0,0};
                vv[j] = z;
            }
        }
#pragma unroll
        for (int jd = 0; jd < 8; ++jd) {
            short4v s4 = {vv[0][jd], vv[1][jd], vv[2][jd], vv[3][jd]};
            *(short4v*)&Vsh[(g * 8 + jd) * VSLOT + i * 24 + cq * 4] = s4;
        }
    }

    const int l15 = lane & 15, l4 = lane >> 4;
    const int y = y0 + w;
    short8v qf = *(const short8v*)(Qp + (size_t)(y * WW + x0 + l15) * HDIM + l4 * 8);
    __syncthreads();

    const int wbase = (min(max(y - 3, 0), HH - 7) - rs) * 24;

    f32x4 sacc[11];
#pragma unroll
    for (int kc = 0; kc < 11; ++kc) {
        short8v kf = *(const short8v*)&Ksh[(wbase + kc * 16 + l15) * LDK + l4 * 8];
        f32x4 z = {0.f, 0.f, 0.f, 0.f};
        sacc[kc] = __builtin_amdgcn_mfma_f32_16x16x32_bf16(kf, qf, z, 0, 0, 0);
    }

    const int xq = x0 + l15;
    const int cw = min(max(xq - 3, 0), WW - 7) - wsx;
    const float scale = 0.17677669529663687f;
    float lsum = 0.f;
#pragma unroll
    for (int kc = 0; kc < 11; ++kc) {
#pragma unroll
        for (int r = 0; r < 4; ++r) {
            int kl = kc * 16 + l4 * 4 + r;
            int row = kl / 24;
            int c = kl - row * 24;
            bool valid = (row < 7) && (c >= cw) && (c <= cw + 6);
            float e = valid ? __expf(sacc[kc][r] * scale) : 0.f;
            sacc[kc][r] = e;
            lsum += e;
        }
    }
    lsum += __shfl_xor(lsum, 16);
    lsum += __shfl_xor(lsum, 32);
    const float inv = 1.0f / lsum;

    short4v pf[12];
#pragma unroll
    for (int kc = 0; kc < 11; ++kc) {
        short4v pk;
#pragma unroll
        for (int r = 0; r < 4; ++r) pk[r] = f2bf(sacc[kc][r] * inv);
        pf[kc] = pk;
    }
    pf[11] = (short4v){0, 0, 0, 0};

    const int src0 = ((l4 & 1) << 5) + l15;
    const int src1 = src0 + 16;
    const bool hi = (l4 & 2) != 0;
    f32x4 oacc[2];
    oacc[0] = (f32x4){0.f, 0.f, 0.f, 0.f};
    oacc[1] = (f32x4){0.f, 0.f, 0.f, 0.f};
#pragma unroll
    for (int kc2 = 0; kc2 < 6; ++kc2) {
        int lo0 = ((const int*)&pf[2 * kc2])[0];
        int lo1 = ((const int*)&pf[2 * kc2])[1];
        int hi0 = ((const int*)&pf[2 * kc2 + 1])[0];
        int hi1 = ((const int*)&pf[2 * kc2 + 1])[1];
        int a0 = __shfl(lo0, src0), a1 = __shfl(lo1, src0);
        int a2 = __shfl(lo0, src1), a3 = __shfl(lo1, src1);
        int b0 = __shfl(hi0, src0), b1 = __shfl(hi1, src0);
        int b2 = __shfl(hi0, src1), b3 = __shfl(hi1, src1);
        int w0 = hi ? b0 : a0, w1 = hi ? b1 : a1;
        int w2 = hi ? b2 : a2, w3 = hi ? b3 : a3;
        int wv[4] = {w0, w1, w2, w3};
        short8v bfrag = *(const short8v*)wv;
#pragma unroll
        for (int nc = 0; nc < 2; ++nc) {
            short8v vf = *(const short8v*)&Vsh[(nc * 16 + l15) * VSLOT
                                               + wbase + kc2 * 32 + l4 * 8];
            oacc[nc] = __builtin_amdgcn_mfma_f32_16x16x32_bf16(vf, bfrag, oacc[nc], 0, 0, 0);
        }
    }

    short* op = attn + (size_t)(y * WW + x0 + l15) * CC + head * HDIM;
#pragma unroll
    for (int nc = 0; nc < 2; ++nc) {
        short4v o;
#pragma unroll
        for (int r = 0; r < 4; ++r) o[r] = f2bf(oacc[nc][r]);
        *(short4v*)(op + nc * 16 + l4 * 4) = o;
    }
}

// ---------------------------------------------------------------------------
// Fused pipeline: prep -> QKV GEMM -> NA -> proj, grid-synced.
// ---------------------------------------------------------------------------
__global__ __launch_bounds__(256, 2)
void fused(const float* __restrict__ x, const float* __restrict__ w_qkv,
           const float* __restrict__ b_qkv, const float* __restrict__ w_proj,
           const float* __restrict__ b_proj, float* __restrict__ out,
           short* __restrict__ x_bf, short* __restrict__ wq_t,
           short* __restrict__ wp_t, short* __restrict__ qkv_r,
           short* __restrict__ attn_bf, u32* syncb)
{
    __shared__ SharedU sh;
    const int bid = blockIdx.x;
    const int tid = threadIdx.x;

    // ---- phase 0: x -> bf16 (1024 units) + weight transposes (256 units) ----
    for (int vb = bid; vb < 1280; vb += (int)NBLK) {
        if (vb < 1024) {
            const int i = vb * 256 + tid;
            float4 a = ((const float4*)x)[i * 2];
            float4 c = ((const float4*)x)[i * 2 + 1];
            short8v o;
            o[0] = f2bf(a.x); o[1] = f2bf(a.y); o[2] = f2bf(a.z); o[3] = f2bf(a.w);
            o[4] = f2bf(c.x); o[5] = f2bf(c.y); o[6] = f2bf(c.z); o[7] = f2bf(c.w);
            ((short8v*)x_bf)[i] = o;
        } else {
            int idx = vb - 1024;
            const float* src; short* dst; int N;
            if (idx < 192) { src = w_qkv;  dst = wq_t; N = QKV_N; }
            else { idx -= 192; src = w_proj; dst = wp_t; N = CC; }
            const int nbx = N / 32;
            const int bn = (idx % nbx) * 32;
            const int bk = (idx / nbx) * 32;
            const int tx = tid & 31, ty = tid >> 5;
#pragma unroll
            for (int i = 0; i < 32; i += 8)
                sh.tile[ty + i][tx] = src[(size_t)(bk + ty + i) * N + bn + tx];
            __syncthreads();
#pragma unroll
            for (int i = 0; i < 32; i += 8)
                dst[(size_t)(bn + ty + i) * CC + bk + tx] = f2bf(sh.tile[tx][ty + i]);
        }
    }
    grid_sync(syncb, 1, bid);

    // ---- phase 1: QKV GEMM, 768 tiles of 64x128 over 512 blocks ----
    for (int vt = bid; vt < 768; vt += (int)NBLK) {
        const int m = vt & 127, n = vt >> 7;
        gemm_tile<64, 128, false, true>(sh.raw, x_bf, wq_t, b_qkv, qkv_r,
                                        QKV_N, CC, m * 64, n * 128);
        __syncthreads();
    }
    grid_sync(syncb, 2, bid);

    // ---- phase 2: neighborhood attention, 1024 tiles over 512 blocks ----
    for (int vt = bid; vt < 1024; vt += (int)NBLK) {
        na_tile(sh.raw, qkv_r, attn_bf, (vt & 7) * 16, ((vt >> 3) & 15) * 4, vt >> 7);
        __syncthreads();
    }
    grid_sync(syncb, 3, bid);

    // ---- phase 3: proj GEMM, 512 tiles of 64x64, 1:1 ----
    {
        const int vt = bid;
        gemm_tile<64, 64, true, false>(sh.raw, attn_bf, wp_t, b_proj, out,
                                       CC, CC, (vt & 127) * 64, (vt >> 7) * 64);
    }
}

// ---------------------------------------------------------------------------
extern "C" void kernel_launch(void* const* d_in, const int* in_sizes, int n_in,
                              void* d_out, int out_size, void* d_ws, size_t ws_size,
                              hipStream_t stream)
{
    const float* x      = (const float*)d_in[0];
    const float* w_qkv  = (const float*)d_in[1];
    const float* b_qkv  = (const float*)d_in[2];
    const float* w_proj = (const float*)d_in[3];
    const float* b_proj = (const float*)d_in[4];
    float* out = (float*)d_out;

    char* ws = (char*)d_ws;
    short* qkv_r   = (short*)ws;                    // 24 planes x 8192 x 32 bf16 = 12 MB
    short* attn_bf = (short*)(ws + 12582912);       // 8192x256 bf16 = 4 MB
    short* x_bf    = (short*)(ws + 16777216);       // 8192x256 bf16 = 4 MB
    short* wq_t    = (short*)(ws + 20971520);       // 768x256 bf16
    short* wp_t    = (short*)(ws + 21364736);       // 256x256 bf16
    u32*   syncb   = (u32*)(ws + 21495808);         // 8 sub + top + flag (1280 B)

    hipMemsetAsync(syncb, 0, 1280, stream);         // zero barrier state each launch
    fused<<<dim3(NBLK), dim3(256), 0, stream>>>(
        x, w_qkv, b_qkv, w_proj, b_proj, out,
        x_bf, wq_t, wp_t, qkv_r, attn_bf, syncb);
}

// Round 9
// 43.890 us; speedup vs baseline: 4.9651x; 2.3523x over previous
//
#include <hip/hip_runtime.h>
#include <cmath>

// B=1, H=64, W=128, C=256, 8 heads x 32 dim, 7x7 window.
#define HH 64
#define WW 128
#define CC 256
#define NHEAD 8
#define HDIM 32
#define NPIX (HH*WW)       // 8192
#define QKV_N (3*CC)       // 768

#define KSLOT 248
#define LDK   40
#define VSLOT 264

typedef __attribute__((ext_vector_type(8))) short short8v;  // 8 bf16
typedef __attribute__((ext_vector_type(4))) short short4v;  // 4 bf16
typedef __attribute__((ext_vector_type(4))) float f32x4;
typedef unsigned int u32;

__device__ __forceinline__ short f2bf(float f) {
    unsigned int u = __builtin_bit_cast(unsigned int, f);
    u += 0x7fffu + ((u >> 16) & 1u);
    return (short)(u >> 16);
}

// ---------------------------------------------------------------------------
// prep_w: weight transposes only (x is consumed fp32 by gemm_qkv now).
//   blocks [0,192): w_qkv [256][768] -> wq_t [768][256] bf16
//   blocks [192,256): w_proj [256][256] -> wp_t [256][256] bf16
// ---------------------------------------------------------------------------
__global__ __launch_bounds__(256)
void prep_w(const float* __restrict__ w_qkv, const float* __restrict__ w_proj,
            short* __restrict__ wq_t, short* __restrict__ wp_t)
{
    __shared__ float tile[32][33];
    int idx = blockIdx.x;
    const float* src; short* dst; int N;
    if (idx < 192) { src = w_qkv;  dst = wq_t; N = QKV_N; }
    else { idx -= 192; src = w_proj; dst = wp_t; N = CC; }
    const int nbx = N / 32;
    const int bn = (idx % nbx) * 32;
    const int bk = (idx / nbx) * 32;
    const int tx = threadIdx.x & 31, ty = threadIdx.x >> 5;
#pragma unroll
    for (int i = 0; i < 32; i += 8)
        tile[ty + i][tx] = src[(size_t)(bk + ty + i) * N + bn + tx];
    __syncthreads();
#pragma unroll
    for (int i = 0; i < 32; i += 8)
        dst[(size_t)(bn + ty + i) * CC + bk + tx] = f2bf(tile[tx][ty + i]);
}

// ---------------------------------------------------------------------------
// QKV GEMM: qkv_plane = x[8192][256](fp32) * wq_t[768][256]^T + b_qkv.
// BM=64 BN=128 BK=32, grid (128,6)=768 blocks, 4 waves 2x2.
// A: fp32 global -> reg -> f2bf -> padded-row LDS (conflict-free b128 reads;
//    identical rounding point to the old x_bf prep => bit-identical output).
// B: global_load_lds double-buffered, LINEAR dest; bank fix via T21
//    pre-swizzled SOURCE granule (g ^= row&3) + same XOR on the frag read
//    (linear 64B rows alone are an 8-way conflict: bank=(row*16+l4*4)%32).
// C: plane layout [24][NPIX][32] so na staging reads are 1KB-contiguous.
// ---------------------------------------------------------------------------
__global__ __launch_bounds__(256)
void gemm_qkv(const float* __restrict__ A, const short* __restrict__ Bt,
              const float* __restrict__ bias, short* __restrict__ Cp)
{
    __shared__ short As[64 * 40];        // padded rows: 80B stride, 2-way max
    __shared__ short Bs[2][128 * 32];    // linear: gload_lds dest

    const int tid = threadIdx.x, lane = tid & 63, wave = tid >> 6;
    const int wm0 = (wave >> 1) * 32, wn0 = (wave & 1) * 64;
    const int bm = blockIdx.x * 64, bn = blockIdx.y * 128;
    const int l15 = lane & 15, l4 = lane >> 4;
    const int arow = tid >> 2, akoff = (tid & 3) * 8;

    f32x4 acc[2][4];
#pragma unroll
    for (int i = 0; i < 2; ++i)
#pragma unroll
        for (int j = 0; j < 4; ++j) acc[i][j] = (f32x4){0.f, 0.f, 0.f, 0.f};

    auto stageB = [&](int buf, int t) {
#pragma unroll
        for (int i = 0; i < 2; ++i) {
            const int g = tid + 256 * i;
            const int row = g >> 2, gr = g & 3;
            __builtin_amdgcn_global_load_lds(
                (const __attribute__((address_space(1))) u32*)
                    (Bt + (size_t)(bn + row) * CC + t * 32 + ((gr ^ (row & 3)) * 8)),
                (__attribute__((address_space(3))) u32*)&Bs[buf][g * 8], 16, 0, 0);
        }
    };

    float4 a0, a1;
    {
        const float* p = A + (size_t)(bm + arow) * CC + akoff;
        a0 = *(const float4*)p; a1 = *(const float4*)(p + 4);
    }
    stageB(0, 0);

    for (int t = 0; t < 8; ++t) {
        const int cur = t & 1;
        __syncthreads();     // prior frag reads done; Bs[cur] loads landed
        {
            short8v w;
            w[0] = f2bf(a0.x); w[1] = f2bf(a0.y); w[2] = f2bf(a0.z); w[3] = f2bf(a0.w);
            w[4] = f2bf(a1.x); w[5] = f2bf(a1.y); w[6] = f2bf(a1.z); w[7] = f2bf(a1.w);
            *(short8v*)&As[arow * 40 + akoff] = w;
        }
        __syncthreads();     // As(t) visible to all waves
        if (t + 1 < 8) {
            const float* p = A + (size_t)(bm + arow) * CC + (t + 1) * 32 + akoff;
            a0 = *(const float4*)p; a1 = *(const float4*)(p + 4);
            stageB(cur ^ 1, t + 1);
        }

        short8v af[2], bf[4];
#pragma unroll
        for (int fm = 0; fm < 2; ++fm)
            af[fm] = *(const short8v*)&As[(wm0 + fm * 16 + l15) * 40 + l4 * 8];
#pragma unroll
        for (int fn = 0; fn < 4; ++fn) {
            const int row = wn0 + fn * 16 + l15;
            bf[fn] = *(const short8v*)&Bs[cur][row * 32 + ((l4 ^ (row & 3)) * 8)];
        }
#pragma unroll
        for (int fm = 0; fm < 2; ++fm)
#pragma unroll
            for (int fn = 0; fn < 4; ++fn)
                acc[fm][fn] = __builtin_amdgcn_mfma_f32_16x16x32_bf16(
                    af[fm], bf[fn], acc[fm][fn], 0, 0, 0);
    }

    const int col0 = bn + wn0 + l15;
    const int row0 = bm + wm0 + l4 * 4;
#pragma unroll
    for (int fn = 0; fn < 4; ++fn) {
        const int cc = col0 + fn * 16;
        const float bv = bias[cc];
#pragma unroll
        for (int fm = 0; fm < 2; ++fm)
#pragma unroll
            for (int r = 0; r < 4; ++r) {
                const int rr = row0 + fm * 16 + r;
                Cp[((size_t)(cc >> 5) * NPIX + rr) * HDIM + (cc & 31)] =
                    f2bf(acc[fm][fn][r] + bv);
            }
    }
}

// ---------------------------------------------------------------------------
// proj GEMM: out = attn_bf[8192][256] * wp_t[256][256]^T + b_proj (fp32 out).
// BM=64 BN=128 BK=32, grid (128,2). Both operands via gload_lds dbuf with the
// T21 source-swizzle (g ^= row&3) + matching XOR on frag reads.
// ---------------------------------------------------------------------------
__global__ __launch_bounds__(256)
void gemm_proj(const short* __restrict__ A, const short* __restrict__ Bt,
               const float* __restrict__ bias, float* __restrict__ C)
{
    __shared__ short As[2][64 * 32];
    __shared__ short Bs[2][128 * 32];

    const int tid = threadIdx.x, lane = tid & 63, wave = tid >> 6;
    const int wm0 = (wave >> 1) * 32, wn0 = (wave & 1) * 64;
    const int bm = blockIdx.x * 64, bn = blockIdx.y * 128;
    const int l15 = lane & 15, l4 = lane >> 4;

    f32x4 acc[2][4];
#pragma unroll
    for (int i = 0; i < 2; ++i)
#pragma unroll
        for (int j = 0; j < 4; ++j) acc[i][j] = (f32x4){0.f, 0.f, 0.f, 0.f};

    auto stage = [&](int buf, int t) {
        {   // A: 256 granules, 1/thread
            const int row = tid >> 2, gr = tid & 3;
            __builtin_amdgcn_global_load_lds(
                (const __attribute__((address_space(1))) u32*)
                    (A + (size_t)(bm + row) * CC + t * 32 + ((gr ^ (row & 3)) * 8)),
                (__attribute__((address_space(3))) u32*)&As[buf][tid * 8], 16, 0, 0);
        }
#pragma unroll
        for (int i = 0; i < 2; ++i) {   // B: 512 granules, 2/thread
            const int g = tid + 256 * i;
            const int row = g >> 2, gr = g & 3;
            __builtin_amdgcn_global_load_lds(
                (const __attribute__((address_space(1))) u32*)
                    (Bt + (size_t)(bn + row) * CC + t * 32 + ((gr ^ (row & 3)) * 8)),
                (__attribute__((address_space(3))) u32*)&Bs[buf][g * 8], 16, 0, 0);
        }
    };

    stage(0, 0);

    for (int t = 0; t < 8; ++t) {
        const int cur = t & 1;
        __syncthreads();                 // stage(t) landed; prior buf reads done
        if (t + 1 < 8) stage(cur ^ 1, t + 1);

        short8v af[2], bf[4];
#pragma unroll
        for (int fm = 0; fm < 2; ++fm) {
            const int row = wm0 + fm * 16 + l15;
            af[fm] = *(const short8v*)&As[cur][row * 32 + ((l4 ^ (row & 3)) * 8)];
        }
#pragma unroll
        for (int fn = 0; fn < 4; ++fn) {
            const int row = wn0 + fn * 16 + l15;
            bf[fn] = *(const short8v*)&Bs[cur][row * 32 + ((l4 ^ (row & 3)) * 8)];
        }
#pragma unroll
        for (int fm = 0; fm < 2; ++fm)
#pragma unroll
            for (int fn = 0; fn < 4; ++fn)
                acc[fm][fn] = __builtin_amdgcn_mfma_f32_16x16x32_bf16(
                    af[fm], bf[fn], acc[fm][fn], 0, 0, 0);
    }

    const int col0 = bn + wn0 + l15;
    const int row0 = bm + wm0 + l4 * 4;
#pragma unroll
    for (int fn = 0; fn < 4; ++fn) {
        const float bv = bias[col0 + fn * 16];
#pragma unroll
        for (int fm = 0; fm < 2; ++fm)
#pragma unroll
            for (int r = 0; r < 4; ++r)
                C[(size_t)(row0 + fm * 16 + r) * CC + col0 + fn * 16] =
                    acc[fm][fn][r] + bv;
    }
}

// ---------------------------------------------------------------------------
// Neighborhood attention (round-6/8 math verbatim; qkv in plane layout
// [24][NPIX][32] so staging reads are 1KB-contiguous per wave).
// ---------------------------------------------------------------------------
__global__ __launch_bounds__(256)
void na_mfma(const short* __restrict__ qkv, short* __restrict__ attn)
{
    __shared__ short Ksh[KSLOT * LDK];   // 19840 B
    __shared__ short Vsh[32 * VSLOT];    // 16896 B  [d][slot]

    const int x0 = blockIdx.x * 16;
    const int y0 = blockIdx.y * 4;
    const int head = blockIdx.z;
    const int tid = threadIdx.x, lane = tid & 63, w = tid >> 6;
    const int rs  = min(max(y0 - 3, 0), HH - 7);
    const int wsx = x0 - 3;
    const short* Qp = qkv + (size_t)head * NPIX * HDIM;
    const short* Kp = qkv + (size_t)(NHEAD + head) * NPIX * HDIM;
    const short* Vp = qkv + (size_t)(2 * NHEAD + head) * NPIX * HDIM;

    for (int idx = tid; idx < 880; idx += 256) {
        int g = idx & 3, rc = idx >> 2;
        int i = rc / 22, c = rc - i * 22;
        int yy = rs + i, xx = wsx + c;
        if (yy < HH && (unsigned)xx < WW)
            *(short8v*)&Ksh[(i * 24 + c) * LDK + g * 8] =
                *(const short8v*)(Kp + (size_t)(yy * WW + xx) * HDIM + g * 8);
    }
    for (int idx = tid; idx < 264; idx += 256) {
        int g = idx & 3, q2 = idx >> 2;
        int i = q2 / 6, cq = q2 - i * 6;
        int yy = rs + i;
        short8v vv[4];
#pragma unroll
        for (int j = 0; j < 4; ++j) {
            int c = cq * 4 + j, xx = wsx + c;
            if (yy < HH && c < 22 && (unsigned)xx < WW)
                vv[j] = *(const short8v*)(Vp + (size_t)(yy * WW + xx) * HDIM + g * 8);
            else {
                short8v z = {0,0,0,0,0,0,0,0};
                vv[j] = z;
            }
        }
#pragma unroll
        for (int jd = 0; jd < 8; ++jd) {
            short4v s4 = {vv[0][jd], vv[1][jd], vv[2][jd], vv[3][jd]};
            *(short4v*)&Vsh[(g * 8 + jd) * VSLOT + i * 24 + cq * 4] = s4;
        }
    }

    const int l15 = lane & 15, l4 = lane >> 4;
    const int y = y0 + w;
    short8v qf = *(const short8v*)(Qp + (size_t)(y * WW + x0 + l15) * HDIM + l4 * 8);
    __syncthreads();

    const int wbase = (min(max(y - 3, 0), HH - 7) - rs) * 24;

    f32x4 sacc[11];
#pragma unroll
    for (int kc = 0; kc < 11; ++kc) {
        short8v kf = *(const short8v*)&Ksh[(wbase + kc * 16 + l15) * LDK + l4 * 8];
        f32x4 z = {0.f, 0.f, 0.f, 0.f};
        sacc[kc] = __builtin_amdgcn_mfma_f32_16x16x32_bf16(kf, qf, z, 0, 0, 0);
    }

    const int xq = x0 + l15;
    const int cw = min(max(xq - 3, 0), WW - 7) - wsx;
    const float scale = 0.17677669529663687f;
    float lsum = 0.f;
#pragma unroll
    for (int kc = 0; kc < 11; ++kc) {
#pragma unroll
        for (int r = 0; r < 4; ++r) {
            int kl = kc * 16 + l4 * 4 + r;
            int row = kl / 24;
            int c = kl - row * 24;
            bool valid = (row < 7) && (c >= cw) && (c <= cw + 6);
            float e = valid ? __expf(sacc[kc][r] * scale) : 0.f;
            sacc[kc][r] = e;
            lsum += e;
        }
    }
    lsum += __shfl_xor(lsum, 16);
    lsum += __shfl_xor(lsum, 32);
    const float inv = 1.0f / lsum;

    short4v pf[12];
#pragma unroll
    for (int kc = 0; kc < 11; ++kc) {
        short4v pk;
#pragma unroll
        for (int r = 0; r < 4; ++r) pk[r] = f2bf(sacc[kc][r] * inv);
        pf[kc] = pk;
    }
    pf[11] = (short4v){0, 0, 0, 0};

    const int src0 = ((l4 & 1) << 5) + l15;
    const int src1 = src0 + 16;
    const bool hi = (l4 & 2) != 0;
    f32x4 oacc[2];
    oacc[0] = (f32x4){0.f, 0.f, 0.f, 0.f};
    oacc[1] = (f32x4){0.f, 0.f, 0.f, 0.f};
#pragma unroll
    for (int kc2 = 0; kc2 < 6; ++kc2) {
        int lo0 = ((const int*)&pf[2 * kc2])[0];
        int lo1 = ((const int*)&pf[2 * kc2])[1];
        int hi0 = ((const int*)&pf[2 * kc2 + 1])[0];
        int hi1 = ((const int*)&pf[2 * kc2 + 1])[1];
        int a0 = __shfl(lo0, src0), a1 = __shfl(lo1, src0);
        int a2 = __shfl(lo0, src1), a3 = __shfl(lo1, src1);
        int b0 = __shfl(hi0, src0), b1 = __shfl(hi1, src0);
        int b2 = __shfl(hi0, src1), b3 = __shfl(hi1, src1);
        int w0 = hi ? b0 : a0, w1 = hi ? b1 : a1;
        int w2 = hi ? b2 : a2, w3 = hi ? b3 : a3;
        int wv[4] = {w0, w1, w2, w3};
        short8v bfrag = *(const short8v*)wv;
#pragma unroll
        for (int nc = 0; nc < 2; ++nc) {
            short8v vf = *(const short8v*)&Vsh[(nc * 16 + l15) * VSLOT
                                               + wbase + kc2 * 32 + l4 * 8];
            oacc[nc] = __builtin_amdgcn_mfma_f32_16x16x32_bf16(vf, bfrag, oacc[nc], 0, 0, 0);
        }
    }

    short* op = attn + (size_t)(y * WW + x0 + l15) * CC + head * HDIM;
#pragma unroll
    for (int nc = 0; nc < 2; ++nc) {
        short4v o;
#pragma unroll
        for (int r = 0; r < 4; ++r) o[r] = f2bf(oacc[nc][r]);
        *(short4v*)(op + nc * 16 + l4 * 4) = o;
    }
}

// ---------------------------------------------------------------------------
extern "C" void kernel_launch(void* const* d_in, const int* in_sizes, int n_in,
                              void* d_out, int out_size, void* d_ws, size_t ws_size,
                              hipStream_t stream)
{
    const float* x      = (const float*)d_in[0];
    const float* w_qkv  = (const float*)d_in[1];
    const float* b_qkv  = (const float*)d_in[2];
    const float* w_proj = (const float*)d_in[3];
    const float* b_proj = (const float*)d_in[4];
    float* out = (float*)d_out;

    char* ws = (char*)d_ws;
    short* qkv_r   = (short*)ws;                    // 24 planes x 8192 x 32 bf16 = 12 MB
    short* attn_bf = (short*)(ws + 12582912);       // 8192x256 bf16 = 4 MB
    short* wq_t    = (short*)(ws + 16777216);       // 768x256 bf16
    short* wp_t    = (short*)(ws + 17170432);       // 256x256 bf16

    // weight transposes (x handled fp32-direct by gemm_qkv)
    prep_w<<<dim3(256), dim3(256), 0, stream>>>(w_qkv, w_proj, wq_t, wp_t);

    // QKV: M=8192, N=768, K=256 -> bf16 planes
    gemm_qkv<<<dim3(NPIX / 64, QKV_N / 128), dim3(256), 0, stream>>>(
        x, wq_t, b_qkv, qkv_r);

    // attention
    na_mfma<<<dim3(WW / 16, HH / 4, NHEAD), dim3(256), 0, stream>>>(qkv_r, attn_bf);

    // proj: M=8192, N=256, K=256 -> fp32 out
    gemm_proj<<<dim3(NPIX / 64, CC / 128), dim3(256), 0, stream>>>(
        attn_bf, wp_t, b_proj, out);
}